// Round 14
// baseline (78.161 us; speedup 1.0000x reference)
//
#include <hip/hip_runtime.h>
#include <hip/hip_bf16.h>

#define STATE 16
#define DNA_C 4
#define HID   128
#define FAN1  52
#define HH    256
#define WW    256
#define HW    (HH * WW)

typedef unsigned short u16;
typedef unsigned int   u32;
typedef short bf8 __attribute__((ext_vector_type(8)));
typedef float f32x4 __attribute__((ext_vector_type(4)));

// two-level LDS chunk swizzle: bijective in c for fixed px; spreads rows AND chunks
#define SWZ(c, p) (((((c) + ((p) >> 3)) & 7)) ^ ((p) & 7))

__device__ __forceinline__ u32 pk(float a, float b) {
    __hip_bfloat162 t = __float22bfloat162_rn(make_float2(a, b));  // v_cvt_pk_bf16_f32
    union { __hip_bfloat162 h; u32 u; } c; c.h = t; return c.u;
}
__device__ __forceinline__ u16 f2bf(float f) {
    union { __hip_bfloat16 h; u16 u; } c; c.h = __float2bfloat16(f); return c.u;
}

// w1 [128][52] f32 -> bf16 [128][64], doubly permuted:
//  * k-layout: knew = 16*c4 + 4*t2 + e  ->  true feat = 16*t2 + (c4+4e) for t2<3 (x/gx/gy),
//    t2==3: e==0 -> dna (48+c4), else zero-pad.  (matches the wave-private feature layout)
//  * M-permutation (hidden reorder, r13): physical row p=16m+4g+r holds true hidden
//    H = 32*(m>>1) + 8g + 4*(m&1) + r  ->  L1 D-frag IS the L2 B-frag (register-only L2).
// w2 [16][128] -> bf16 plain.
__global__ void prep_weights(const float* __restrict__ w1, const float* __restrict__ w2,
                             u16* __restrict__ wb) {
    int i = blockIdx.x * 256 + threadIdx.x;   // 0..10239
    if (i < 128 * 64) {
        int p = i >> 6, knew = i & 63;
        int m = p >> 4, g = (p >> 2) & 3, r = p & 3;
        int hrow = 32 * (m >> 1) + 8 * g + 4 * (m & 1) + r;
        int c4 = knew >> 4, t2 = (knew >> 2) & 3, e = knew & 3;
        float v = 0.f;
        if (t2 < 3)       v = w1[hrow * FAN1 + 16 * t2 + c4 + 4 * e];
        else if (e == 0)  v = w1[hrow * FAN1 + 48 + c4];
        wb[i] = f2bf(v);
    } else if (i < 128 * 64 + 16 * 128) {
        wb[i] = f2bf(w2[i - 128 * 64]);
    }
}

__global__ __launch_bounds__(256, 3) void update_net14(
    const float* __restrict__ x,    // [B,16,256,256]
    const float* __restrict__ dna,  // [B,4,256,256]
    const u16*   __restrict__ wb,   // permuted bf16 w1 [128][64], w2 [16][128]
    float* __restrict__ out,        // [B,16,256,256]
    int nrows)                      // B*256
{
    // Wave-private feat: [64 px][64 k] bf16 per wave (8 KB), chunks swizzled SWZ. 32 KB total.
    // NO __syncthreads anywhere: each wave computes features for its own 64-px segment
    // (all 16 channels), writes its own LDS region, reads it back for MFMA.
    // Rows are processed in a grid-stride loop; in-order per-wave DS makes next-row
    // ds_writes safe against this-row ds_reads with no fences.
    __shared__ __align__(16) u16 feat_lds[4][64 * 64];

    const int tid  = threadIdx.x;
    const int lane = tid & 63;
    const int wv   = tid >> 6;
    const int c4   = lane >> 4;     // channel sub-index (feature phase) == fg (MLP)
    const int p16  = lane & 15;     // px-group (feature)              == fj (MLP)
    const int fj   = p16, fg = c4;
    const int px0  = wv * 64;       // wave's global px base

    // ---- weight fragments once per block (L1/L2-hot) ----
    const u16* w1b = wb;             // [128][64] doubly permuted
    const u16* w2b = wb + 128 * 64;  // [16][128]
    bf8 a1[8][2];
    #pragma unroll
    for (int m = 0; m < 8; ++m) {
        #pragma unroll
        for (int kt = 0; kt < 2; ++kt)
            a1[m][kt] = *(const bf8*)&w1b[(16 * m + fj) * 64 + 32 * kt + 8 * fg];
    }
    bf8 a2[4];
    #pragma unroll
    for (int kt = 0; kt < 4; ++kt)
        a2[kt] = *(const bf8*)&w2b[fj * 128 + 32 * kt + 8 * fg];

    u16* fw = &feat_lds[wv][0];

    // segment-edge halo: lane p16==0 needs px0-1, lane p16==15 needs px0+64
    const int  eoff = (p16 == 0) ? -1 : 4;     // offset from lane's own base pointer
    const bool pe   = (p16 == 0) ? (wv > 0) : ((p16 == 15) ? (wv < 3) : false);

    for (int yr = blockIdx.x; yr < nrows; yr += gridDim.x) {
        const int b = yr >> 8;
        const int y = yr & 255;
        const bool ht = (y > 0), hb = (y < HH - 1);
        const int pxl = px0 + 4 * p16;

        // ---- feature rounds: t=0..3, lane handles channel c4+4t, 4 px ----
        f32x4 sx[4], sgx[4], sgy[4];
        #pragma unroll
        for (int t = 0; t < 4; ++t) {
            const float* p = x + (((size_t)(b * STATE + c4 + 4 * t)) * HH + y) * WW + pxl;
            f32x4 m4 = *(const f32x4*)p;
            f32x4 t4 = {0.f,0.f,0.f,0.f}, b4 = {0.f,0.f,0.f,0.f};
            if (ht) t4 = *(const f32x4*)(p - WW);
            if (hb) b4 = *(const f32x4*)(p + WW);
            float mE = 0.f, tE = 0.f, bE = 0.f;
            if (pe) {
                mE = p[eoff];
                if (ht) tE = p[eoff - WW];
                if (hb) bE = p[eoff + WW];
            }
            f32x4 cs, d;
            #pragma unroll
            for (int i = 0; i < 4; ++i) {
                cs[i] = fmaf(2.f, m4[i], t4[i] + b4[i]);   // colsum t+2m+b
                d[i]  = b4[i] - t4[i];
            }
            const float csE = fmaf(2.f, mE, tE + bE);
            const float dE  = bE - tE;
            float csL = __shfl_up(cs[3], 1);
            float csR = __shfl_down(cs[0], 1);
            float dL  = __shfl_up(d[3], 1);
            float dR  = __shfl_down(d[0], 1);
            if (p16 == 0)  { csL = csE; dL = dE; }   // segment/image left edge
            if (p16 == 15) { csR = csE; dR = dE; }   // segment/image right edge
            sx[t] = m4;
            sgx[t][0] = cs[1] - csL;   sgx[t][1] = cs[2] - cs[0];
            sgx[t][2] = cs[3] - cs[1]; sgx[t][3] = csR - cs[2];
            sgy[t][0] = fmaf(2.f, d[0], dL + d[1]);
            sgy[t][1] = fmaf(2.f, d[1], d[0] + d[2]);
            sgy[t][2] = fmaf(2.f, d[2], d[1] + d[3]);
            sgy[t][3] = fmaf(2.f, d[3], d[2] + dR);
        }
        const f32x4 dn = *(const f32x4*)(dna + (((size_t)(b * DNA_C + c4)) * HH + y) * WW + pxl);

        // ---- LDS writes: lane owns k [16c4, 16c4+16) of its 4 px -> 2 b128 per px ----
        #pragma unroll
        for (int i = 0; i < 4; ++i) {
            const int px = 4 * p16 + i;   // local row
            uint4 q0 = make_uint4(pk(sx[0][i],  sx[1][i]),  pk(sx[2][i],  sx[3][i]),
                                  pk(sgx[0][i], sgx[1][i]), pk(sgx[2][i], sgx[3][i]));
            uint4 q1 = make_uint4(pk(sgy[0][i], sgy[1][i]), pk(sgy[2][i], sgy[3][i]),
                                  pk(dn[i], 0.f), 0u);
            *(uint4*)&fw[px * 64 + 8 * SWZ(2 * c4,     px)] = q0;   // k 16c4..+7 : x|gx
            *(uint4*)&fw[px * 64 + 8 * SWZ(2 * c4 + 1, px)] = q1;   // k +8..+15 : gy|dna
        }

        // ---- MLP per g4 (wave-private reads; in-order DS orders vs next-row writes) ----
        #pragma unroll
        for (int g4 = 0; g4 < 4; ++g4) {
            const int r = g4 * 16 + fj;   // local row
            bf8 b0 = *(const bf8*)&fw[r * 64 + 8 * SWZ(fg,     r)];
            bf8 b1 = *(const bf8*)&fw[r * 64 + 8 * SWZ(4 + fg, r)];

            u32 w[8][2];
            #pragma unroll
            for (int mh = 0; mh < 2; ++mh) {
                f32x4 hc[4];
                #pragma unroll
                for (int mm = 0; mm < 4; ++mm) {
                    const int m = mh * 4 + mm;
                    f32x4 z = {0.f, 0.f, 0.f, 0.f};
                    z = __builtin_amdgcn_mfma_f32_16x16x32_bf16(a1[m][0], b0, z, 0, 0, 0);
                    hc[mm] = __builtin_amdgcn_mfma_f32_16x16x32_bf16(a1[m][1], b1, z, 0, 0, 0);
                }
                #pragma unroll
                for (int mm = 0; mm < 4; ++mm) {
                    const int m = mh * 4 + mm;
                    w[m][0] = pk(fmaxf(hc[mm][0], 0.f), fmaxf(hc[mm][1], 0.f));
                    w[m][1] = pk(fmaxf(hc[mm][2], 0.f), fmaxf(hc[mm][3], 0.f));
                }
            }

            // layer 2: B-fragment from the lane's own words (register-only, r13)
            f32x4 uacc = {0.f, 0.f, 0.f, 0.f};
            #pragma unroll
            for (int kt = 0; kt < 4; ++kt) {
                union { u32 u[4]; bf8 v; } bb;
                bb.u[0] = w[2 * kt][0];
                bb.u[1] = w[2 * kt][1];
                bb.u[2] = w[2 * kt + 1][0];
                bb.u[3] = w[2 * kt + 1][1];
                uacc = __builtin_amdgcn_mfma_f32_16x16x32_bf16(a2[kt], bb.v, uacc, 0, 0, 0);
            }

            const int xo = px0 + g4 * 16 + fj;
            float* po = out + (((size_t)(b * STATE + 4 * fg)) * HH + y) * WW + xo;
            #pragma unroll
            for (int rr = 0; rr < 4; ++rr)
                po[(size_t)rr * HW] = uacc[rr];
        }
    }
}

extern "C" void kernel_launch(void* const* d_in, const int* in_sizes, int n_in,
                              void* d_out, int out_size, void* d_ws, size_t ws_size,
                              hipStream_t stream) {
    const float* x   = (const float*)d_in[0];
    const float* dna = (const float*)d_in[1];
    const float* w1  = (const float*)d_in[2];
    const float* w2  = (const float*)d_in[3];
    float* out = (float*)d_out;
    u16* wb = (u16*)d_ws;   // 10240 u16 = 20 KB

    prep_weights<<<dim3(40), dim3(256), 0, stream>>>(w1, w2, wb);

    const int B = in_sizes[0] / (STATE * HH * WW);   // 16
    const int nrows = B * HH;                        // 4096
    const int grid = (nrows < 768) ? nrows : 768;    // 3 blocks/CU persistent
    update_net14<<<dim3(grid), dim3(256), 0, stream>>>(x, dna, wb, out, nrows);
}